// Round 3
// baseline (261.361 us; speedup 1.0000x reference)
//
#include <hip/hip_runtime.h>

#define LOG2E 1.4426950408889634f

typedef __bf16 bf16x8 __attribute__((ext_vector_type(8)));
typedef float f32x4 __attribute__((ext_vector_type(4)));

__device__ __forceinline__ unsigned short bfb(__bf16 b){
  union { __bf16 b; unsigned short u; } z; z.b = b; return z.u;
}
__device__ __forceinline__ void split8(const float* __restrict__ p, bf16x8& hi, bf16x8& lo){
  #pragma unroll
  for (int j = 0; j < 8; j++){
    float f = p[j];
    __bf16 h = (__bf16)f;
    hi[j] = h;
    lo[j] = (__bf16)(f - (float)h);
  }
}

// ---------------- prep kernels (fp32 in) ----------------
// W2[n=h*64+e][k] = 2*log2e * sum_c A[e][c] * W[h*64+c][k], split into bf16 hi+lo
__global__ __launch_bounds__(256) void prep_w2(
    const float* __restrict__ Wq, const float* __restrict__ Aq,
    const float* __restrict__ Wk, const float* __restrict__ Ak,
    unsigned short* __restrict__ W2q_hi, unsigned short* __restrict__ W2q_lo,
    unsigned short* __restrict__ W2k_hi, unsigned short* __restrict__ W2k_lo){
  const float* W  = blockIdx.y ? Wk : Wq;
  const float* Am = blockIdx.y ? Ak : Aq;
  unsigned short* WH = blockIdx.y ? W2k_hi : W2q_hi;
  unsigned short* WL = blockIdx.y ? W2k_lo : W2q_lo;
  int idx = blockIdx.x * 256 + threadIdx.x;   // 0..262143
  int n = idx >> 9, k = idx & 511;
  int h = n >> 6, e = n & 63;
  float acc = 0.f;
  #pragma unroll 8
  for (int c = 0; c < 64; c++)
    acc += Am[e*64 + c] * W[(h*64 + c)*512 + k];
  float v = acc * (2.f * LOG2E);
  __bf16 hb = (__bf16)v;
  WH[n*512 + k] = bfb(hb);
  WL[n*512 + k] = bfb((__bf16)(v - (float)hb));
}

__global__ void prep_b(const float* __restrict__ bq, const float* __restrict__ Aq,
                       const float* __restrict__ bk, const float* __restrict__ Ak,
                       float* __restrict__ b2q, float* __restrict__ b2k){
  int n = blockIdx.x * 256 + threadIdx.x;    // 0..511
  int h = n >> 6, e = n & 63;
  float aq = 0.f, ak = 0.f;
  for (int c = 0; c < 64; c++){
    aq += Aq[e*64 + c] * bq[h*64 + c];
    ak += Ak[e*64 + c] * bk[h*64 + c];
  }
  b2q[n] = aq * (2.f * LOG2E);
  b2k[n] = ak * (2.f * LOG2E);
}

// ---------------- MFMA GEMM: C[1024][512] = A[1024][512] * B[n][k]^T + bias ----------------
// All paths hi/lo-split (error ~2^-18 rel): 3 MFMA per 16x16 tile-step.
struct GemmBatch {
  const float* Af;            // fp32 A [1024][512]
  const unsigned short* Bhi;  // pre-split bf16 B hi (if Bf==null)
  const unsigned short* Blo;  // pre-split bf16 B lo
  const float* Bf;            // fp32 B [n][k] (split in-register if non-null)
  const float* bias;          // [512] fp32
  float* Cf;                  // fp32 out [1024][512]
};
struct GemmArgs { GemmBatch g[3]; };

__global__ __launch_bounds__(256) void gemm_nk(GemmArgs ga){
  GemmBatch gb = ga.g[blockIdx.z];
  const int lane = threadIdx.x & 63;
  const int w    = threadIdx.x >> 6;
  const int l15  = lane & 15, quad = lane >> 4;
  const int m  = blockIdx.x * 64 + w * 16 + l15;
  const int nb = blockIdx.y * 64 + l15;
  const float* Arow = gb.Af + (size_t)m * 512;
  f32x4 ac0 = {0.f,0.f,0.f,0.f}, ac1 = ac0, ac2 = ac0, ac3 = ac0;

  #pragma unroll 2
  for (int ks = 0; ks < 16; ks++){
    int ko = ks * 32 + quad * 8;
    bf16x8 ah, al;
    split8(Arow + ko, ah, al);
    #pragma unroll
    for (int t = 0; t < 4; t++){
      bf16x8 bh, bl;
      if (gb.Bf){
        split8(gb.Bf + (size_t)(nb + t*16) * 512 + ko, bh, bl);
      } else {
        bh = *(const bf16x8*)(gb.Bhi + (size_t)(nb + t*16) * 512 + ko);
        bl = *(const bf16x8*)(gb.Blo + (size_t)(nb + t*16) * 512 + ko);
      }
      f32x4& ac = (t==0)?ac0:(t==1)?ac1:(t==2)?ac2:ac3;
      ac = __builtin_amdgcn_mfma_f32_16x16x32_bf16(ah, bh, ac, 0, 0, 0);
      ac = __builtin_amdgcn_mfma_f32_16x16x32_bf16(al, bh, ac, 0, 0, 0);
      ac = __builtin_amdgcn_mfma_f32_16x16x32_bf16(ah, bl, ac, 0, 0, 0);
    }
  }

  const int mrow = blockIdx.x * 64 + w * 16 + quad * 4;  // C/D: col=lane&15, row=quad*4+reg
  #pragma unroll
  for (int t = 0; t < 4; t++){
    f32x4 v = (t==0)?ac0:(t==1)?ac1:(t==2)?ac2:ac3;
    int n = blockIdx.y * 64 + t * 16 + l15;
    float bs = gb.bias[n];
    #pragma unroll
    for (int r = 0; r < 4; r++)
      gb.Cf[(size_t)(mrow + r) * 512 + n] = v[r] + bs;
  }
}

// ---------------- fused additive-attention core ----------------
// grid (64, 16): x = query-block of 8 rows, y = b*8+h. block = 256 (4 waves, 2 rows per wave)
__global__ __launch_bounds__(256) void attn_kernel(
    const float* __restrict__ qp, const float* __restrict__ kp,
    const float* __restrict__ Vv, const float* __restrict__ av_in,
    float* __restrict__ Oh){
  __shared__ float smem[12992];
  float* kv  = smem;          // score phase: kpT [64][130]; PV phase: V [128][64]
  float* qp8 = smem + 8320;   // [8][64]
  float* av2 = smem + 8832;   // [64]
  float* pb  = smem + 8896;   // [8][512] unnormalized exp2(scores)
  const int tid = threadIdx.x, lane = tid & 63, w = tid >> 6;
  const int b = blockIdx.y >> 3, h = blockIdx.y & 7;
  const int i0 = blockIdx.x * 8;
  const size_t base = ((size_t)b * 512) * 512 + (size_t)h * 64; // + row*512 + d

  {
    int il = tid >> 6, d = tid & 63;
    qp8[il * 64 + d]       = qp[base + (size_t)(i0 + il) * 512 + d];
    qp8[(il + 4) * 64 + d] = qp[base + (size_t)(i0 + il + 4) * 512 + d];
    if (tid < 64) av2[tid] = -2.0f * LOG2E * av_in[tid];
  }
  const int il0 = w * 2, il1 = il0 + 1;
  float dena = 0.f, denb = 0.f;

  for (int c = 0; c < 4; c++){
    __syncthreads();
    { // stage kp chunk transposed: kv[d][jl], stride 130
      int d = tid & 63, jr = tid >> 6;
      #pragma unroll
      for (int it = 0; it < 32; it++){
        int jl = it * 4 + jr;
        kv[d * 130 + jl] = kp[base + (size_t)(c * 128 + jl) * 512 + d];
      }
    }
    __syncthreads();
    float s00 = 0.f, s01 = 0.f, s10 = 0.f, s11 = 0.f;
    #pragma unroll 8
    for (int d = 0; d < 64; d++){
      float2 kk = *(const float2*)&kv[d * 130 + 2 * lane];
      float qa = qp8[il0 * 64 + d];
      float qb = qp8[il1 * 64 + d];
      float a2 = av2[d];
      s00 += a2 * __builtin_amdgcn_rcpf(1.f + __builtin_amdgcn_exp2f(qa + kk.x));
      s01 += a2 * __builtin_amdgcn_rcpf(1.f + __builtin_amdgcn_exp2f(qa + kk.y));
      s10 += a2 * __builtin_amdgcn_rcpf(1.f + __builtin_amdgcn_exp2f(qb + kk.x));
      s11 += a2 * __builtin_amdgcn_rcpf(1.f + __builtin_amdgcn_exp2f(qb + kk.y));
    }
    float e00 = __builtin_amdgcn_exp2f(s00);
    float e01 = __builtin_amdgcn_exp2f(s01);
    float e10 = __builtin_amdgcn_exp2f(s10);
    float e11 = __builtin_amdgcn_exp2f(s11);
    dena += e00 + e01; denb += e10 + e11;
    int jb = c * 128 + 2 * lane;
    *(float2*)&pb[il0 * 512 + jb] = make_float2(e00, e01);
    *(float2*)&pb[il1 * 512 + jb] = make_float2(e10, e11);
  }

  #pragma unroll
  for (int off = 1; off < 64; off <<= 1){
    dena += __shfl_xor(dena, off, 64);
    denb += __shfl_xor(denb, off, 64);
  }
  float inva = __builtin_amdgcn_rcpf(dena);
  float invb = __builtin_amdgcn_rcpf(denb);

  float acc0 = 0.f, acc1 = 0.f;
  for (int c = 0; c < 4; c++){
    __syncthreads();
    { // stage V chunk row-major: kv[jl][d]
      int d = tid & 63, jr = tid >> 6;
      #pragma unroll
      for (int it = 0; it < 32; it++){
        int jl = it * 4 + jr;
        kv[jl * 64 + d] = Vv[base + (size_t)(c * 128 + jl) * 512 + d];
      }
    }
    __syncthreads();
    #pragma unroll 8
    for (int jl = 0; jl < 128; jl += 4){
      float4 pa  = *(const float4*)&pb[il0 * 512 + c * 128 + jl];
      float4 pbv = *(const float4*)&pb[il1 * 512 + c * 128 + jl];
      float v0 = kv[(jl + 0) * 64 + lane];
      float v1 = kv[(jl + 1) * 64 + lane];
      float v2 = kv[(jl + 2) * 64 + lane];
      float v3 = kv[(jl + 3) * 64 + lane];
      acc0 += pa.x  * v0 + pa.y  * v1 + pa.z  * v2 + pa.w  * v3;
      acc1 += pbv.x * v0 + pbv.y * v1 + pbv.z * v2 + pbv.w * v3;
    }
  }
  Oh[base + (size_t)(i0 + il0) * 512 + lane] = acc0 * inva;
  Oh[base + (size_t)(i0 + il1) * 512 + lane] = acc1 * invb;
}

// ---------------- launch ----------------
extern "C" void kernel_launch(void* const* d_in, const int* in_sizes, int n_in,
                              void* d_out, int out_size, void* d_ws, size_t ws_size,
                              hipStream_t stream){
  const float* q_in = (const float*)d_in[0];
  const float* k_in = (const float*)d_in[1];
  const float* v_in = (const float*)d_in[2];
  const float* Wq_  = (const float*)d_in[3];
  const float* bq_  = (const float*)d_in[4];
  const float* Wk_  = (const float*)d_in[5];
  const float* bk_  = (const float*)d_in[6];
  const float* Wv_  = (const float*)d_in[7];
  const float* bv_  = (const float*)d_in[8];
  const float* Wo_  = (const float*)d_in[9];
  const float* bo_  = (const float*)d_in[10];
  const float* Aq_  = (const float*)d_in[11];
  const float* Ak_  = (const float*)d_in[12];
  const float* av_  = (const float*)d_in[13];

  char* ws = (char*)d_ws;
  // [0 .. 2MB): W2 splits during projection phase; reused as Oh (fp32 2MB) afterwards
  unsigned short* W2q_hi = (unsigned short*)(ws + 0);
  unsigned short* W2q_lo = (unsigned short*)(ws + 524288);
  unsigned short* W2k_hi = (unsigned short*)(ws + 1048576);
  unsigned short* W2k_lo = (unsigned short*)(ws + 1572864);
  float* Oh  = (float*)(ws + 0);
  float* b2q = (float*)(ws + 2097152);
  float* b2k = (float*)(ws + 2099200);
  float* qp  = (float*)(ws + 2101248);
  float* kp  = (float*)(ws + 2101248 + 2097152);
  float* Vw  = (float*)(ws + 2101248 + 2*2097152);

  prep_w2<<<dim3(1024, 2, 1), 256, 0, stream>>>(Wq_, Aq_, Wk_, Ak_,
                                                W2q_hi, W2q_lo, W2k_hi, W2k_lo);
  prep_b<<<dim3(2, 1, 1), 256, 0, stream>>>(bq_, Aq_, bk_, Ak_, b2q, b2k);

  GemmArgs ga;
  ga.g[0] = { q_in, W2q_hi, W2q_lo, nullptr, b2q, qp };
  ga.g[1] = { k_in, W2k_hi, W2k_lo, nullptr, b2k, kp };
  ga.g[2] = { v_in, nullptr, nullptr, Wv_,   bv_, Vw };
  gemm_nk<<<dim3(16, 8, 3), 256, 0, stream>>>(ga);

  attn_kernel<<<dim3(64, 16, 1), 256, 0, stream>>>(qp, kp, Vw, av_, Oh);

  GemmArgs go;
  go.g[0] = { Oh, nullptr, nullptr, Wo_, bo_, (float*)d_out };
  go.g[1] = go.g[0];
  go.g[2] = go.g[0];
  gemm_nk<<<dim3(16, 8, 1), 256, 0, stream>>>(go);
}

// Round 4
// 252.646 us; speedup vs baseline: 1.0345x; 1.0345x over previous
//
#include <hip/hip_runtime.h>

#define LOG2E 1.4426950408889634f

typedef __bf16 bf16x8 __attribute__((ext_vector_type(8)));
typedef float f32x4 __attribute__((ext_vector_type(4)));

__device__ __forceinline__ unsigned short bfb(__bf16 b){
  union { __bf16 b; unsigned short u; } z; z.b = b; return z.u;
}
__device__ __forceinline__ void split8(const float* __restrict__ p, bf16x8& hi, bf16x8& lo){
  #pragma unroll
  for (int j = 0; j < 8; j++){
    float f = p[j];
    __bf16 h = (__bf16)f;
    hi[j] = h;
    lo[j] = (__bf16)(f - (float)h);
  }
}

// ---------------- prep kernels (fp32 in) ----------------
// W2[n=h*64+e][k] = 2*log2e * sum_c A[e][c] * W[h*64+c][k], split into bf16 hi+lo
__global__ __launch_bounds__(256) void prep_w2(
    const float* __restrict__ Wq, const float* __restrict__ Aq,
    const float* __restrict__ Wk, const float* __restrict__ Ak,
    unsigned short* __restrict__ W2q_hi, unsigned short* __restrict__ W2q_lo,
    unsigned short* __restrict__ W2k_hi, unsigned short* __restrict__ W2k_lo){
  const float* W  = blockIdx.y ? Wk : Wq;
  const float* Am = blockIdx.y ? Ak : Aq;
  unsigned short* WH = blockIdx.y ? W2k_hi : W2q_hi;
  unsigned short* WL = blockIdx.y ? W2k_lo : W2q_lo;
  int idx = blockIdx.x * 256 + threadIdx.x;   // 0..262143
  int n = idx >> 9, k = idx & 511;
  int h = n >> 6, e = n & 63;
  float acc = 0.f;
  #pragma unroll 8
  for (int c = 0; c < 64; c++)
    acc += Am[e*64 + c] * W[(h*64 + c)*512 + k];
  float v = acc * (2.f * LOG2E);
  __bf16 hb = (__bf16)v;
  WH[n*512 + k] = bfb(hb);
  WL[n*512 + k] = bfb((__bf16)(v - (float)hb));
}

__global__ void prep_b(const float* __restrict__ bq, const float* __restrict__ Aq,
                       const float* __restrict__ bk, const float* __restrict__ Ak,
                       float* __restrict__ b2q, float* __restrict__ b2k){
  int n = blockIdx.x * 256 + threadIdx.x;    // 0..511
  int h = n >> 6, e = n & 63;
  float aq = 0.f, ak = 0.f;
  for (int c = 0; c < 64; c++){
    aq += Aq[e*64 + c] * bq[h*64 + c];
    ak += Ak[e*64 + c] * bk[h*64 + c];
  }
  b2q[n] = aq * (2.f * LOG2E);
  b2k[n] = ak * (2.f * LOG2E);
}

// ---------------- MFMA GEMM: C[1024][512] = A[1024][512] * B[n][k]^T + bias ----------------
struct GemmBatch {
  const float* Af;            // fp32 A [1024][512]
  const unsigned short* Bhi;  // pre-split bf16 B hi (if Bf==null)
  const unsigned short* Blo;  // pre-split bf16 B lo
  const float* Bf;            // fp32 B [n][k] (split in-register if non-null)
  const float* bias;          // [512] fp32
  float* Cf;                  // fp32 out [1024][512]
};
struct GemmArgs { GemmBatch g[3]; };

__global__ __launch_bounds__(256) void gemm_nk(GemmArgs ga){
  GemmBatch gb = ga.g[blockIdx.z];
  const int lane = threadIdx.x & 63;
  const int w    = threadIdx.x >> 6;
  const int l15  = lane & 15, quad = lane >> 4;
  const int m  = blockIdx.x * 64 + w * 16 + l15;
  const int nb = blockIdx.y * 64 + l15;
  const float* Arow = gb.Af + (size_t)m * 512;
  f32x4 ac0 = {0.f,0.f,0.f,0.f}, ac1 = ac0, ac2 = ac0, ac3 = ac0;

  #pragma unroll 2
  for (int ks = 0; ks < 16; ks++){
    int ko = ks * 32 + quad * 8;
    bf16x8 ah, al;
    split8(Arow + ko, ah, al);
    #pragma unroll
    for (int t = 0; t < 4; t++){
      bf16x8 bh, bl;
      if (gb.Bf){
        split8(gb.Bf + (size_t)(nb + t*16) * 512 + ko, bh, bl);
      } else {
        bh = *(const bf16x8*)(gb.Bhi + (size_t)(nb + t*16) * 512 + ko);
        bl = *(const bf16x8*)(gb.Blo + (size_t)(nb + t*16) * 512 + ko);
      }
      f32x4& ac = (t==0)?ac0:(t==1)?ac1:(t==2)?ac2:ac3;
      ac = __builtin_amdgcn_mfma_f32_16x16x32_bf16(ah, bh, ac, 0, 0, 0);
      ac = __builtin_amdgcn_mfma_f32_16x16x32_bf16(al, bh, ac, 0, 0, 0);
      ac = __builtin_amdgcn_mfma_f32_16x16x32_bf16(ah, bl, ac, 0, 0, 0);
    }
  }

  const int mrow = blockIdx.x * 64 + w * 16 + quad * 4;  // C/D: col=lane&15, row=quad*4+reg
  #pragma unroll
  for (int t = 0; t < 4; t++){
    f32x4 v = (t==0)?ac0:(t==1)?ac1:(t==2)?ac2:ac3;
    int n = blockIdx.y * 64 + t * 16 + l15;
    float bs = gb.bias[n];
    #pragma unroll
    for (int r = 0; r < 4; r++)
      gb.Cf[(size_t)(mrow + r) * 512 + n] = v[r] + bs;
  }
}

// ---------------- fused additive-attention core (online PV) ----------------
// grid (64, 16): x = 8-row query block, y = b*8+h. block = 256 = 4 waves, 2 rows/wave.
// LDS 39424 B -> 4 blocks/CU -> all 1024 blocks co-resident (zero tail).
__global__ __launch_bounds__(256) void attn_kernel(
    const float* __restrict__ qp, const float* __restrict__ kp,
    const float* __restrict__ Vv, const float* __restrict__ av_in,
    float* __restrict__ Oh){
  __shared__ float smem[9856];
  float* kv  = smem;          // score phase: kpT [64][129]; PV phase: V [128][64]
  float* pc  = smem + 8256;   // [8][128] per-chunk unnormalized exp2(scores)
  float* qp8 = smem + 9280;   // [8][64]
  float* av2 = smem + 9792;   // [64]
  const int tid = threadIdx.x, lane = tid & 63, w = tid >> 6;
  const int b = blockIdx.y >> 3, h = blockIdx.y & 7;
  const int i0 = blockIdx.x * 8;
  const size_t base = ((size_t)b * 512) * 512 + (size_t)h * 64; // + row*512 + d

  {
    int il = tid >> 6, d = tid & 63;
    qp8[il * 64 + d]       = qp[base + (size_t)(i0 + il) * 512 + d];
    qp8[(il + 4) * 64 + d] = qp[base + (size_t)(i0 + il + 4) * 512 + d];
    if (tid < 64) av2[tid] = -2.0f * LOG2E * av_in[tid];
  }
  const int il0 = w * 2, il1 = il0 + 1;
  float den0 = 0.f, den1 = 0.f, acc0 = 0.f, acc1 = 0.f;

  for (int c = 0; c < 4; c++){
    __syncthreads();   // kv (V of prev chunk) fully consumed; pc consumed
    { // stage kp chunk transposed: kv[d*129 + jl]  (129 odd => 2-way banks, free)
      int d = tid & 63, jr = tid >> 6;
      #pragma unroll
      for (int it = 0; it < 32; it++){
        int jl = it * 4 + jr;
        kv[d * 129 + jl] = kp[base + (size_t)(c * 128 + jl) * 512 + d];
      }
    }
    __syncthreads();
    float s00 = 0.f, s01 = 0.f, s10 = 0.f, s11 = 0.f;
    #pragma unroll 8
    for (int d = 0; d < 64; d++){
      float k0 = kv[d * 129 + 2 * lane];
      float k1 = kv[d * 129 + 2 * lane + 1];
      float qa = qp8[il0 * 64 + d];
      float qb = qp8[il1 * 64 + d];
      float a2 = av2[d];
      s00 += a2 * __builtin_amdgcn_rcpf(1.f + __builtin_amdgcn_exp2f(qa + k0));
      s01 += a2 * __builtin_amdgcn_rcpf(1.f + __builtin_amdgcn_exp2f(qa + k1));
      s10 += a2 * __builtin_amdgcn_rcpf(1.f + __builtin_amdgcn_exp2f(qb + k0));
      s11 += a2 * __builtin_amdgcn_rcpf(1.f + __builtin_amdgcn_exp2f(qb + k1));
    }
    float e00 = __builtin_amdgcn_exp2f(s00);
    float e01 = __builtin_amdgcn_exp2f(s01);
    float e10 = __builtin_amdgcn_exp2f(s10);
    float e11 = __builtin_amdgcn_exp2f(s11);
    den0 += e00 + e01; den1 += e10 + e11;
    *(float2*)&pc[il0 * 128 + 2 * lane] = make_float2(e00, e01);
    *(float2*)&pc[il1 * 128 + 2 * lane] = make_float2(e10, e11);
    __syncthreads();   // kv (kpT) consumed, pc written
    { // stage V chunk row-major: kv[jl*64 + d]
      int d = tid & 63, jr = tid >> 6;
      #pragma unroll
      for (int it = 0; it < 32; it++){
        int jl = it * 4 + jr;
        kv[jl * 64 + d] = Vv[base + (size_t)(c * 128 + jl) * 512 + d];
      }
    }
    __syncthreads();
    #pragma unroll 8
    for (int jl = 0; jl < 128; jl += 4){
      float4 pa  = *(const float4*)&pc[il0 * 128 + jl];
      float4 pbv = *(const float4*)&pc[il1 * 128 + jl];
      float v0 = kv[(jl + 0) * 64 + lane];
      float v1 = kv[(jl + 1) * 64 + lane];
      float v2 = kv[(jl + 2) * 64 + lane];
      float v3 = kv[(jl + 3) * 64 + lane];
      acc0 += pa.x  * v0 + pa.y  * v1 + pa.z  * v2 + pa.w  * v3;
      acc1 += pbv.x * v0 + pbv.y * v1 + pbv.z * v2 + pbv.w * v3;
    }
  }

  #pragma unroll
  for (int off = 1; off < 64; off <<= 1){
    den0 += __shfl_xor(den0, off, 64);
    den1 += __shfl_xor(den1, off, 64);
  }
  Oh[base + (size_t)(i0 + il0) * 512 + lane] = acc0 / den0;
  Oh[base + (size_t)(i0 + il1) * 512 + lane] = acc1 / den1;
}

// ---------------- launch ----------------
extern "C" void kernel_launch(void* const* d_in, const int* in_sizes, int n_in,
                              void* d_out, int out_size, void* d_ws, size_t ws_size,
                              hipStream_t stream){
  const float* q_in = (const float*)d_in[0];
  const float* k_in = (const float*)d_in[1];
  const float* v_in = (const float*)d_in[2];
  const float* Wq_  = (const float*)d_in[3];
  const float* bq_  = (const float*)d_in[4];
  const float* Wk_  = (const float*)d_in[5];
  const float* bk_  = (const float*)d_in[6];
  const float* Wv_  = (const float*)d_in[7];
  const float* bv_  = (const float*)d_in[8];
  const float* Wo_  = (const float*)d_in[9];
  const float* bo_  = (const float*)d_in[10];
  const float* Aq_  = (const float*)d_in[11];
  const float* Ak_  = (const float*)d_in[12];
  const float* av_  = (const float*)d_in[13];

  char* ws = (char*)d_ws;
  // [0 .. 2MB): W2 splits during projection phase; reused as Oh (fp32 2MB) afterwards
  unsigned short* W2q_hi = (unsigned short*)(ws + 0);
  unsigned short* W2q_lo = (unsigned short*)(ws + 524288);
  unsigned short* W2k_hi = (unsigned short*)(ws + 1048576);
  unsigned short* W2k_lo = (unsigned short*)(ws + 1572864);
  float* Oh  = (float*)(ws + 0);
  float* b2q = (float*)(ws + 2097152);
  float* b2k = (float*)(ws + 2099200);
  float* qp  = (float*)(ws + 2101248);
  float* kp  = (float*)(ws + 2101248 + 2097152);
  float* Vw  = (float*)(ws + 2101248 + 2*2097152);

  prep_w2<<<dim3(1024, 2, 1), 256, 0, stream>>>(Wq_, Aq_, Wk_, Ak_,
                                                W2q_hi, W2q_lo, W2k_hi, W2k_lo);
  prep_b<<<dim3(2, 1, 1), 256, 0, stream>>>(bq_, Aq_, bk_, Ak_, b2q, b2k);

  GemmArgs ga;
  ga.g[0] = { q_in, W2q_hi, W2q_lo, nullptr, b2q, qp };
  ga.g[1] = { k_in, W2k_hi, W2k_lo, nullptr, b2k, kp };
  ga.g[2] = { v_in, nullptr, nullptr, Wv_,   bv_, Vw };
  gemm_nk<<<dim3(16, 8, 3), 256, 0, stream>>>(ga);

  attn_kernel<<<dim3(64, 16, 1), 256, 0, stream>>>(qp, kp, Vw, av_, Oh);

  GemmArgs go;
  go.g[0] = { Oh, nullptr, nullptr, Wo_, bo_, (float*)d_out };
  go.g[1] = go.g[0];
  go.g[2] = go.g[0];
  gemm_nk<<<dim3(16, 8, 1), 256, 0, stream>>>(go);
}

// Round 5
// 247.743 us; speedup vs baseline: 1.0550x; 1.0198x over previous
//
#include <hip/hip_runtime.h>

#define LOG2E 1.4426950408889634f

typedef __bf16 bf16x8 __attribute__((ext_vector_type(8)));
typedef float f32x4 __attribute__((ext_vector_type(4)));

__device__ __forceinline__ unsigned short bfb(__bf16 b){
  union { __bf16 b; unsigned short u; } z; z.b = b; return z.u;
}
__device__ __forceinline__ void split8(const float* __restrict__ p, bf16x8& hi, bf16x8& lo){
  #pragma unroll
  for (int j = 0; j < 8; j++){
    float f = p[j];
    __bf16 h = (__bf16)f;
    hi[j] = h;
    lo[j] = (__bf16)(f - (float)h);
  }
}

// ---------------- prep: W2 hi/lo splits + folded biases + av2 ----------------
// grid (1025, 2): x<1024 -> W2 elements; x==1024,y==0 -> biases; x==1024,y==1 -> av2g
__global__ __launch_bounds__(256) void prep_all(
    const float* __restrict__ Wq, const float* __restrict__ Aq,
    const float* __restrict__ Wk, const float* __restrict__ Ak,
    const float* __restrict__ bq, const float* __restrict__ bk,
    const float* __restrict__ av,
    unsigned short* __restrict__ W2q_hi, unsigned short* __restrict__ W2q_lo,
    unsigned short* __restrict__ W2k_hi, unsigned short* __restrict__ W2k_lo,
    float* __restrict__ b2q, float* __restrict__ b2k, float* __restrict__ av2g){
  if (blockIdx.x == 1024){
    if (blockIdx.y == 0){
      #pragma unroll
      for (int rep = 0; rep < 2; rep++){
        int n = rep * 256 + threadIdx.x;    // 0..511
        int h = n >> 6, e = n & 63;
        float aq = 0.f, ak = 0.f;
        for (int c = 0; c < 64; c++){
          aq += Aq[e*64 + c] * bq[h*64 + c];
          ak += Ak[e*64 + c] * bk[h*64 + c];
        }
        b2q[n] = aq * (2.f * LOG2E);
        b2k[n] = ak * (2.f * LOG2E);
      }
    } else {
      if (threadIdx.x < 64) av2g[threadIdx.x] = -2.f * LOG2E * av[threadIdx.x];
    }
    return;
  }
  const float* W  = blockIdx.y ? Wk : Wq;
  const float* Am = blockIdx.y ? Ak : Aq;
  unsigned short* WH = blockIdx.y ? W2k_hi : W2q_hi;
  unsigned short* WL = blockIdx.y ? W2k_lo : W2q_lo;
  int idx = blockIdx.x * 256 + threadIdx.x;   // 0..262143
  int n = idx >> 9, k = idx & 511;
  int h = n >> 6, e = n & 63;
  float acc = 0.f;
  #pragma unroll 8
  for (int c = 0; c < 64; c++)
    acc += Am[e*64 + c] * W[(h*64 + c)*512 + k];
  float v = acc * (2.f * LOG2E);
  __bf16 hb = (__bf16)v;
  WH[n*512 + k] = bfb(hb);
  WL[n*512 + k] = bfb((__bf16)(v - (float)hb));
}

// ---------------- MFMA GEMM: C[1024][512] = A[1024][512] * B[n][k]^T + bias ----------------
struct GemmBatch {
  const float* Af;            // fp32 A [1024][512]
  const unsigned short* Bhi;  // pre-split bf16 B hi (if Bf==null)
  const unsigned short* Blo;  // pre-split bf16 B lo
  const float* Bf;            // fp32 B [n][k] (split in-register if non-null)
  const float* bias;          // [512] fp32
  float* Cf;                  // fp32 out
  int transposed;             // 1: write qpT layout ((b*8+h)*64+dk)*512 + i
};
struct GemmArgs { GemmBatch g[3]; };

__global__ __launch_bounds__(256) void gemm_nk(GemmArgs ga){
  GemmBatch gb = ga.g[blockIdx.z];
  const int lane = threadIdx.x & 63;
  const int w    = threadIdx.x >> 6;
  const int l15  = lane & 15, quad = lane >> 4;
  const int m  = blockIdx.x * 64 + w * 16 + l15;
  const int nb = blockIdx.y * 64 + l15;
  const float* Arow = gb.Af + (size_t)m * 512;
  f32x4 ac0 = {0.f,0.f,0.f,0.f}, ac1 = ac0, ac2 = ac0, ac3 = ac0;

  #pragma unroll 2
  for (int ks = 0; ks < 16; ks++){
    int ko = ks * 32 + quad * 8;
    bf16x8 ah, al;
    split8(Arow + ko, ah, al);
    #pragma unroll
    for (int t = 0; t < 4; t++){
      bf16x8 bh, bl;
      if (gb.Bf){
        split8(gb.Bf + (size_t)(nb + t*16) * 512 + ko, bh, bl);
      } else {
        bh = *(const bf16x8*)(gb.Bhi + (size_t)(nb + t*16) * 512 + ko);
        bl = *(const bf16x8*)(gb.Blo + (size_t)(nb + t*16) * 512 + ko);
      }
      f32x4& ac = (t==0)?ac0:(t==1)?ac1:(t==2)?ac2:ac3;
      ac = __builtin_amdgcn_mfma_f32_16x16x32_bf16(ah, bh, ac, 0, 0, 0);
      ac = __builtin_amdgcn_mfma_f32_16x16x32_bf16(al, bh, ac, 0, 0, 0);
      ac = __builtin_amdgcn_mfma_f32_16x16x32_bf16(ah, bl, ac, 0, 0, 0);
    }
  }

  const int mrow = blockIdx.x * 64 + w * 16 + quad * 4;  // C/D: col=lane&15, row=quad*4+reg
  #pragma unroll
  for (int t = 0; t < 4; t++){
    f32x4 v = (t==0)?ac0:(t==1)?ac1:(t==2)?ac2:ac3;
    int n = blockIdx.y * 64 + t * 16 + l15;
    float bs = gb.bias[n];
    #pragma unroll
    for (int r = 0; r < 4; r++){
      float val = v[r] + bs;
      int m2 = mrow + r;
      if (gb.transposed){
        // qpT[((b*8 + h)*64 + dk)*512 + i],  b=m2>>9, i=m2&511, h=n>>6, dk=n&63
        gb.Cf[(size_t)(((m2 >> 9) * 8 + (n >> 6)) * 64 + (n & 63)) * 512 + (m2 & 511)] = val;
      } else {
        gb.Cf[(size_t)m2 * 512 + n] = val;
      }
    }
  }
}

// ---------------- fused additive-attention core (LDS-minimized) ----------------
// grid (64,16): x = 8-row query block, y = bh. 256 thr = 4 waves.
// waves 0,1: rows 0-3 (d-halves 0,1); waves 2,3: rows 4-7. lane j = 2*lane, 2*lane+1.
// K/V staged transposed [d][j] stride 130; q + av via wave-uniform global (SMEM) loads.
__global__ __launch_bounds__(256) void attn_kernel(
    const float* __restrict__ qpT, const float* __restrict__ kp,
    const float* __restrict__ Vv, const float* __restrict__ av2g,
    float* __restrict__ Oh){
  __shared__ float smem[9352];
  float* kT = smem;            // [64][130]  (kpT, then vT per chunk)
  float* pc = smem + 8320;     // [8][128]   partial scores -> e values
  float* dn = smem + 9344;     // [8]
  float* accb = smem;          // alias of kT for final combine

  const int tid = threadIdx.x, lane = tid & 63, w = tid >> 6;
  const int bh = blockIdx.y;
  const int i0 = blockIdx.x * 8;
  const size_t kbase = (size_t)(bh >> 3) * 512 * 512 + (size_t)(bh & 7) * 64;
  const int r0  = __builtin_amdgcn_readfirstlane((w >> 1) * 4);
  const int dh0 = __builtin_amdgcn_readfirstlane((w & 1) * 32);
  const size_t qbase = (size_t)bh * 64 * 512 + i0 + r0;   // + d*512

  float s[8];
  #pragma unroll
  for (int r = 0; r < 8; r++) s[r] = 0.f;
  float den4[4] = {0.f, 0.f, 0.f, 0.f};
  float acc[8];
  #pragma unroll
  for (int r = 0; r < 8; r++) acc[r] = 0.f;

  for (int c = 0; c < 4; c++){
    __syncthreads();                      // prev chunk's PV done with kT/pc
    { // stage kp chunk transposed: kT[d*130 + j], d = lane
      #pragma unroll
      for (int m = 0; m < 16; m++){
        int i = w + 4 * m;                // j-pair index 0..63
        float a = kp[kbase + (size_t)(c*128 + 2*i    ) * 512 + lane];
        float b = kp[kbase + (size_t)(c*128 + 2*i + 1) * 512 + lane];
        *(float2*)&kT[lane * 130 + 2*i] = make_float2(a, b);
      }
    }
    __syncthreads();
    { // score partials over this wave's d-half
      #pragma unroll 4
      for (int dd = 0; dd < 32; dd++){
        int d = dh0 + dd;
        float4 qv = *(const float4*)(qpT + qbase + (size_t)d * 512);  // uniform -> s_load
        float a2 = av2g[d];                                           // uniform
        float2 kk = *(const float2*)&kT[d * 130 + 2 * lane];
        float q0 = qv.x, q1 = qv.y, q2 = qv.z, q3 = qv.w;
        s[0] += a2 * __builtin_amdgcn_rcpf(1.f + __builtin_amdgcn_exp2f(q0 + kk.x));
        s[1] += a2 * __builtin_amdgcn_rcpf(1.f + __builtin_amdgcn_exp2f(q0 + kk.y));
        s[2] += a2 * __builtin_amdgcn_rcpf(1.f + __builtin_amdgcn_exp2f(q1 + kk.x));
        s[3] += a2 * __builtin_amdgcn_rcpf(1.f + __builtin_amdgcn_exp2f(q1 + kk.y));
        s[4] += a2 * __builtin_amdgcn_rcpf(1.f + __builtin_amdgcn_exp2f(q2 + kk.x));
        s[5] += a2 * __builtin_amdgcn_rcpf(1.f + __builtin_amdgcn_exp2f(q2 + kk.y));
        s[6] += a2 * __builtin_amdgcn_rcpf(1.f + __builtin_amdgcn_exp2f(q3 + kk.x));
        s[7] += a2 * __builtin_amdgcn_rcpf(1.f + __builtin_amdgcn_exp2f(q3 + kk.y));
      }
      if (w & 1){ // odd d-half waves publish partials
        #pragma unroll
        for (int r = 0; r < 4; r++)
          *(float2*)&pc[(r0 + r) * 128 + 2 * lane] = make_float2(s[2*r], s[2*r+1]);
      }
      #pragma unroll
      for (int r = 0; r < 8; r++){ float t = s[r]; s[r] = 0.f; s[r] = t; } // keep live
    }
    __syncthreads();                      // kT free; partials visible
    { // stage V chunk transposed into kT (all waves)
      #pragma unroll
      for (int m = 0; m < 16; m++){
        int i = w + 4 * m;
        float a = Vv[kbase + (size_t)(c*128 + 2*i    ) * 512 + lane];
        float b = Vv[kbase + (size_t)(c*128 + 2*i + 1) * 512 + lane];
        *(float2*)&kT[lane * 130 + 2*i] = make_float2(a, b);
      }
    }
    if (!(w & 1)){ // even waves: combine halves, exp2, publish e, accumulate den
      #pragma unroll
      for (int r = 0; r < 4; r++){
        float2 o = *(const float2*)&pc[(r0 + r) * 128 + 2 * lane];
        float e0 = __builtin_amdgcn_exp2f(s[2*r]     + o.x);
        float e1 = __builtin_amdgcn_exp2f(s[2*r + 1] + o.y);
        den4[r] += e0 + e1;
        *(float2*)&pc[(r0 + r) * 128 + 2 * lane] = make_float2(e0, e1);
      }
    }
    #pragma unroll
    for (int r = 0; r < 8; r++) s[r] = 0.f;
    __syncthreads();                      // vT + e ready
    { // PV: wave handles j-quarter, all 8 rows, d = lane
      int jq = w * 32;
      #pragma unroll
      for (int g = 0; g < 8; g++){
        int jb = jq + g * 4;
        float2 v01 = *(const float2*)&kT[lane * 130 + jb];
        float2 v23 = *(const float2*)&kT[lane * 130 + jb + 2];
        #pragma unroll
        for (int r = 0; r < 8; r++){
          float4 p = *(const float4*)&pc[r * 128 + jb];   // uniform broadcast
          acc[r] += p.x * v01.x + p.y * v01.y + p.z * v23.x + p.w * v23.y;
        }
      }
    }
  }

  // den reduction (even waves own rows r0..r0+3)
  if (!(w & 1)){
    #pragma unroll
    for (int r = 0; r < 4; r++){
      #pragma unroll
      for (int off = 1; off < 64; off <<= 1)
        den4[r] += __shfl_xor(den4[r], off, 64);
    }
    if (lane == 0){
      #pragma unroll
      for (int r = 0; r < 4; r++) dn[r0 + r] = den4[r];
    }
  }
  __syncthreads();          // PV done with kT; dn visible
  #pragma unroll
  for (int r = 0; r < 8; r++) accb[(w * 8 + r) * 64 + lane] = acc[r];
  __syncthreads();
  #pragma unroll
  for (int rr = 0; rr < 2; rr++){
    int r = w * 2 + rr;
    float sum = accb[(0*8 + r) * 64 + lane] + accb[(1*8 + r) * 64 + lane]
              + accb[(2*8 + r) * 64 + lane] + accb[(3*8 + r) * 64 + lane];
    Oh[kbase + (size_t)(i0 + r) * 512 + lane] = sum / dn[r];
  }
}

// ---------------- launch ----------------
extern "C" void kernel_launch(void* const* d_in, const int* in_sizes, int n_in,
                              void* d_out, int out_size, void* d_ws, size_t ws_size,
                              hipStream_t stream){
  const float* q_in = (const float*)d_in[0];
  const float* k_in = (const float*)d_in[1];
  const float* v_in = (const float*)d_in[2];
  const float* Wq_  = (const float*)d_in[3];
  const float* bq_  = (const float*)d_in[4];
  const float* Wk_  = (const float*)d_in[5];
  const float* bk_  = (const float*)d_in[6];
  const float* Wv_  = (const float*)d_in[7];
  const float* bv_  = (const float*)d_in[8];
  const float* Wo_  = (const float*)d_in[9];
  const float* bo_  = (const float*)d_in[10];
  const float* Aq_  = (const float*)d_in[11];
  const float* Ak_  = (const float*)d_in[12];
  const float* av_  = (const float*)d_in[13];

  char* ws = (char*)d_ws;
  // [0 .. 2MB): W2 splits during projection phase; reused as Oh (fp32 2MB) afterwards
  unsigned short* W2q_hi = (unsigned short*)(ws + 0);
  unsigned short* W2q_lo = (unsigned short*)(ws + 524288);
  unsigned short* W2k_hi = (unsigned short*)(ws + 1048576);
  unsigned short* W2k_lo = (unsigned short*)(ws + 1572864);
  float* Oh   = (float*)(ws + 0);
  float* b2q  = (float*)(ws + 2097152);
  float* b2k  = (float*)(ws + 2099200);
  float* av2g = (float*)(ws + 2101248);
  float* qpT  = (float*)(ws + 2101504);
  float* kp   = (float*)(ws + 2101504 + 2097152);
  float* Vw   = (float*)(ws + 2101504 + 2*2097152);

  prep_all<<<dim3(1025, 2, 1), 256, 0, stream>>>(Wq_, Aq_, Wk_, Ak_, bq_, bk_, av_,
                                                 W2q_hi, W2q_lo, W2k_hi, W2k_lo,
                                                 b2q, b2k, av2g);

  GemmArgs ga;
  ga.g[0] = { q_in, W2q_hi, W2q_lo, nullptr, b2q, qpT, 1 };
  ga.g[1] = { k_in, W2k_hi, W2k_lo, nullptr, b2k, kp,  0 };
  ga.g[2] = { v_in, nullptr, nullptr, Wv_,   bv_, Vw,  0 };
  gemm_nk<<<dim3(16, 8, 3), 256, 0, stream>>>(ga);

  attn_kernel<<<dim3(64, 16, 1), 256, 0, stream>>>(qpT, kp, Vw, av2g, Oh);

  GemmArgs go;
  go.g[0] = { Oh, nullptr, nullptr, Wo_, bo_, (float*)d_out, 0 };
  go.g[1] = go.g[0];
  go.g[2] = go.g[0];
  gemm_nk<<<dim3(16, 8, 1), 256, 0, stream>>>(go);
}

// Round 7
// 228.161 us; speedup vs baseline: 1.1455x; 1.0858x over previous
//
#include <hip/hip_runtime.h>

#define LOG2E 1.4426950408889634f

typedef __bf16 bf16x8 __attribute__((ext_vector_type(8)));
typedef float f32x4 __attribute__((ext_vector_type(4)));

__device__ __forceinline__ unsigned short bfb(__bf16 b){
  union { __bf16 b; unsigned short u; } z; z.b = b; return z.u;
}
__device__ __forceinline__ void split8(const float* __restrict__ p, bf16x8& hi, bf16x8& lo){
  #pragma unroll
  for (int j = 0; j < 8; j++){
    float f = p[j];
    __bf16 h = (__bf16)f;
    hi[j] = h;
    lo[j] = (__bf16)(f - (float)h);
  }
}

// ---------------- split2: fp32 -> bf16 hi/lo for Wv, Wo (262144 elements each) ----------
struct SplitArgs { const float* src[2]; unsigned short* hi[2]; unsigned short* lo[2]; };
__global__ __launch_bounds__(256) void split2(SplitArgs sa){
  const float* src = sa.src[blockIdx.y];
  unsigned short* hi = sa.hi[blockIdx.y];
  unsigned short* lo = sa.lo[blockIdx.y];
  int base = (blockIdx.x * 256 + threadIdx.x) * 4;   // 256 x-blocks -> 262144 elements
  float4 v = *(const float4*)(src + base);
  ushort4 h, l;
  float f; __bf16 hb;
  f = v.x; hb = (__bf16)f; h.x = bfb(hb); l.x = bfb((__bf16)(f - (float)hb));
  f = v.y; hb = (__bf16)f; h.y = bfb(hb); l.y = bfb((__bf16)(f - (float)hb));
  f = v.z; hb = (__bf16)f; h.z = bfb(hb); l.z = bfb((__bf16)(f - (float)hb));
  f = v.w; hb = (__bf16)f; h.w = bfb(hb); l.w = bfb((__bf16)(f - (float)hb));
  *(ushort4*)(hi + base) = h;
  *(ushort4*)(lo + base) = l;
}

// ---------------- prep: W2 fold+split + folded biases + av2 ----------------
__global__ __launch_bounds__(256) void prep_all(
    const float* __restrict__ Wq, const float* __restrict__ Aq,
    const float* __restrict__ Wk, const float* __restrict__ Ak,
    const float* __restrict__ bq, const float* __restrict__ bk,
    const float* __restrict__ av,
    unsigned short* __restrict__ W2q_hi, unsigned short* __restrict__ W2q_lo,
    unsigned short* __restrict__ W2k_hi, unsigned short* __restrict__ W2k_lo,
    float* __restrict__ b2q, float* __restrict__ b2k, float* __restrict__ av2g){
  if (blockIdx.x == 1024){
    if (blockIdx.y == 0){
      #pragma unroll
      for (int rep = 0; rep < 2; rep++){
        int n = rep * 256 + threadIdx.x;
        int h = n >> 6, e = n & 63;
        float aq = 0.f, ak = 0.f;
        for (int c = 0; c < 64; c++){
          aq += Aq[e*64 + c] * bq[h*64 + c];
          ak += Ak[e*64 + c] * bk[h*64 + c];
        }
        b2q[n] = aq * (2.f * LOG2E);
        b2k[n] = ak * (2.f * LOG2E);
      }
    } else {
      if (threadIdx.x < 64) av2g[threadIdx.x] = -2.f * LOG2E * av[threadIdx.x];
    }
    return;
  }
  const float* W  = blockIdx.y ? Wk : Wq;
  const float* Am = blockIdx.y ? Ak : Aq;
  unsigned short* WH = blockIdx.y ? W2k_hi : W2q_hi;
  unsigned short* WL = blockIdx.y ? W2k_lo : W2q_lo;
  int idx = blockIdx.x * 256 + threadIdx.x;
  int n = idx >> 9, k = idx & 511;
  int h = n >> 6, e = n & 63;
  float acc = 0.f;
  #pragma unroll 8
  for (int c = 0; c < 64; c++)
    acc += Am[e*64 + c] * W[(h*64 + c)*512 + k];
  float v = acc * (2.f * LOG2E);
  __bf16 hb = (__bf16)v;
  WH[n*512 + k] = bfb(hb);
  WL[n*512 + k] = bfb((__bf16)(v - (float)hb));
}

// ---------------- MFMA GEMM: C[1024][512] = A(fp32) * B^T(pre-split hi/lo) + bias ----------
struct GemmBatch {
  const float* Af;                 // fp32 A [1024][512]
  const unsigned short *Bh, *Bl;   // bf16 hi/lo B [n][k]
  const float* bias;               // [512]
  float* Cf;                       // fp32 out
  int transposed;                  // 1: qpT layout ((b*8+h)*64+dk)*512 + i
};
struct GemmArgs { GemmBatch g[3]; };

__global__ __launch_bounds__(256) void gemm_nk(GemmArgs ga){
  GemmBatch gb = ga.g[blockIdx.z];
  const int lane = threadIdx.x & 63;
  const int w    = threadIdx.x >> 6;
  const int l15  = lane & 15, quad = lane >> 4;
  const int m  = blockIdx.x * 64 + w * 16 + l15;
  const int nb = blockIdx.y * 64 + l15;
  const float* Arow = gb.Af + (size_t)m * 512;
  f32x4 ac0 = {0.f,0.f,0.f,0.f}, ac1 = ac0, ac2 = ac0, ac3 = ac0;

  #pragma unroll 2
  for (int ks = 0; ks < 16; ks++){
    int ko = ks * 32 + quad * 8;
    bf16x8 ah, al;
    split8(Arow + ko, ah, al);
    #pragma unroll
    for (int t = 0; t < 4; t++){
      bf16x8 bh = *(const bf16x8*)(gb.Bh + (size_t)(nb + t*16) * 512 + ko);
      bf16x8 bl = *(const bf16x8*)(gb.Bl + (size_t)(nb + t*16) * 512 + ko);
      f32x4& ac = (t==0)?ac0:(t==1)?ac1:(t==2)?ac2:ac3;
      ac = __builtin_amdgcn_mfma_f32_16x16x32_bf16(ah, bh, ac, 0, 0, 0);
      ac = __builtin_amdgcn_mfma_f32_16x16x32_bf16(al, bh, ac, 0, 0, 0);
      ac = __builtin_amdgcn_mfma_f32_16x16x32_bf16(ah, bl, ac, 0, 0, 0);
    }
  }

  const int mrow = blockIdx.x * 64 + w * 16 + quad * 4;  // C/D: col=l15, row=quad*4+reg
  #pragma unroll
  for (int t = 0; t < 4; t++){
    f32x4 v = (t==0)?ac0:(t==1)?ac1:(t==2)?ac2:ac3;
    int n = blockIdx.y * 64 + t * 16 + l15;
    float bs = gb.bias[n];
    #pragma unroll
    for (int r = 0; r < 4; r++){
      float val = v[r] + bs;
      int m2 = mrow + r;
      if (gb.transposed){
        gb.Cf[(size_t)(((m2 >> 9) * 8 + (n >> 6)) * 64 + (n & 63)) * 512 + (m2 & 511)] = val;
      } else {
        gb.Cf[(size_t)m2 * 512 + n] = val;
      }
    }
  }
}

// ---------------- fused additive-attention core (MFMA PV) ----------------
// grid (32,16): x = 16-row query block, y = bh. 512 thr = 8 waves.
// Score: wave w owns rows 2w,2w+1 (full d, j = 2*lane,2*lane+1).
// PV (MFMA 16x16x32): wave w -> ntile = w&3 (d block), khalf = w>>2 (k-steps).
__global__ __launch_bounds__(512) void attn_kernel(
    const float* __restrict__ qpT, const float* __restrict__ kp,
    const float* __restrict__ Vv, const float* __restrict__ av2g,
    float* __restrict__ Oh){
  __shared__ float kT[64 * 130];                 // K then V (fp32, stride 130)
  __shared__ unsigned short pcb[2 * 16 * 136];   // P bf16 [hi/lo][row][136]
  __shared__ float dn[16];
  float* cmb = kT;                                // final-combine alias

  const int tid = threadIdx.x, lane = tid & 63, w = tid >> 6;
  const int l15 = lane & 15, quad = lane >> 4;
  const int bh = blockIdx.y;
  const int i0 = blockIdx.x * 16;
  const size_t kbase = (size_t)(bh >> 3) * 512 * 512 + (size_t)(bh & 7) * 64;
  const int r0 = __builtin_amdgcn_readfirstlane(2 * w);
  const size_t qbase = (size_t)bh * 64 * 512 + i0 + r0;
  const int ntile = w & 3, khalf = w >> 2;

  float den0 = 0.f, den1 = 0.f;
  f32x4 Cacc = {0.f, 0.f, 0.f, 0.f};

  for (int c = 0; c < 4; c++){
    __syncthreads();                              // prev PV done with kT/pcb
    { // stage K chunk transposed: kT[d*130 + j], lane = d
      #pragma unroll
      for (int m = 0; m < 8; m++){
        int i = w + 8 * m;                        // j-pair 0..63
        float a = kp[kbase + (size_t)(c*128 + 2*i    ) * 512 + lane];
        float b = kp[kbase + (size_t)(c*128 + 2*i + 1) * 512 + lane];
        *(float2*)&kT[lane * 130 + 2*i] = make_float2(a, b);
      }
    }
    __syncthreads();
    float s00 = 0.f, s01 = 0.f, s10 = 0.f, s11 = 0.f;
    #pragma unroll 4
    for (int d = 0; d < 64; d++){
      float2 qv = *(const float2*)(qpT + qbase + (size_t)d * 512);  // wave-uniform
      float a2 = av2g[d];                                           // wave-uniform
      float2 kk = *(const float2*)&kT[d * 130 + 2 * lane];
      s00 += a2 * __builtin_amdgcn_rcpf(1.f + __builtin_amdgcn_exp2f(qv.x + kk.x));
      s01 += a2 * __builtin_amdgcn_rcpf(1.f + __builtin_amdgcn_exp2f(qv.x + kk.y));
      s10 += a2 * __builtin_amdgcn_rcpf(1.f + __builtin_amdgcn_exp2f(qv.y + kk.x));
      s11 += a2 * __builtin_amdgcn_rcpf(1.f + __builtin_amdgcn_exp2f(qv.y + kk.y));
    }
    float e00 = __builtin_amdgcn_exp2f(s00);
    float e01 = __builtin_amdgcn_exp2f(s01);
    float e10 = __builtin_amdgcn_exp2f(s10);
    float e11 = __builtin_amdgcn_exp2f(s11);
    den0 += e00 + e01; den1 += e10 + e11;
    { // publish P hi/lo bf16 for rows r0, r0+1
      __bf16 h00 = (__bf16)e00, h01 = (__bf16)e01, h10 = (__bf16)e10, h11 = (__bf16)e11;
      ushort2 hi0 = { bfb(h00), bfb(h01) };
      ushort2 hi1 = { bfb(h10), bfb(h11) };
      ushort2 lo0 = { bfb((__bf16)(e00 - (float)h00)), bfb((__bf16)(e01 - (float)h01)) };
      ushort2 lo1 = { bfb((__bf16)(e10 - (float)h10)), bfb((__bf16)(e11 - (float)h11)) };
      *(ushort2*)&pcb[(0*16 + r0    ) * 136 + 2*lane] = hi0;
      *(ushort2*)&pcb[(0*16 + r0 + 1) * 136 + 2*lane] = hi1;
      *(ushort2*)&pcb[(1*16 + r0    ) * 136 + 2*lane] = lo0;
      *(ushort2*)&pcb[(1*16 + r0 + 1) * 136 + 2*lane] = lo1;
    }
    __syncthreads();                              // kT free; pcb published
    { // stage V chunk transposed into kT
      #pragma unroll
      for (int m = 0; m < 8; m++){
        int i = w + 8 * m;
        float a = Vv[kbase + (size_t)(c*128 + 2*i    ) * 512 + lane];
        float b = Vv[kbase + (size_t)(c*128 + 2*i + 1) * 512 + lane];
        *(float2*)&kT[lane * 130 + 2*i] = make_float2(a, b);
      }
    }
    __syncthreads();                              // vT + pcb ready
    { // PV MFMA: C[m=row][n=d], k = j
      #pragma unroll
      for (int kk2 = 0; kk2 < 2; kk2++){
        int k0 = (khalf * 2 + kk2) * 32 + quad * 8;
        bf16x8 ph = *(const bf16x8*)&pcb[(0*16 + l15) * 136 + k0];
        bf16x8 pl = *(const bf16x8*)&pcb[(1*16 + l15) * 136 + k0];
        const float* vp = &kT[(ntile*16 + l15) * 130 + k0];
        bf16x8 vh, vl;
        #pragma unroll
        for (int j = 0; j < 8; j++){
          float f = vp[j];
          __bf16 h = (__bf16)f;
          vh[j] = h; vl[j] = (__bf16)(f - (float)h);
        }
        Cacc = __builtin_amdgcn_mfma_f32_16x16x32_bf16(ph, vh, Cacc, 0, 0, 0);
        Cacc = __builtin_amdgcn_mfma_f32_16x16x32_bf16(pl, vh, Cacc, 0, 0, 0);
        Cacc = __builtin_amdgcn_mfma_f32_16x16x32_bf16(ph, vl, Cacc, 0, 0, 0);
      }
    }
  }

  // den reduction: wave w owns rows 2w, 2w+1
  #pragma unroll
  for (int off = 1; off < 64; off <<= 1){
    den0 += __shfl_xor(den0, off, 64);
    den1 += __shfl_xor(den1, off, 64);
  }
  if (lane == 0){ dn[r0] = den0; dn[r0 + 1] = den1; }
  __syncthreads();                                // PV done with kT; dn visible
  if (w >= 4){
    #pragma unroll
    for (int r = 0; r < 4; r++) cmb[(w - 4) * 256 + lane * 4 + r] = Cacc[r];
  }
  __syncthreads();
  if (w < 4){
    #pragma unroll
    for (int r = 0; r < 4; r++){
      float cv = Cacc[r] + cmb[w * 256 + lane * 4 + r];
      int row = quad * 4 + r;
      int d = ntile * 16 + l15;                   // ntile == w here
      Oh[kbase + (size_t)(i0 + row) * 512 + d] = cv / dn[row];
    }
  }
}

// ---------------- launch ----------------
extern "C" void kernel_launch(void* const* d_in, const int* in_sizes, int n_in,
                              void* d_out, int out_size, void* d_ws, size_t ws_size,
                              hipStream_t stream){
  const float* q_in = (const float*)d_in[0];
  const float* k_in = (const float*)d_in[1];
  const float* v_in = (const float*)d_in[2];
  const float* Wq_  = (const float*)d_in[3];
  const float* bq_  = (const float*)d_in[4];
  const float* Wk_  = (const float*)d_in[5];
  const float* bk_  = (const float*)d_in[6];
  const float* Wv_  = (const float*)d_in[7];
  const float* bv_  = (const float*)d_in[8];
  const float* Wo_  = (const float*)d_in[9];
  const float* bo_  = (const float*)d_in[10];
  const float* Aq_  = (const float*)d_in[11];
  const float* Ak_  = (const float*)d_in[12];
  const float* av_  = (const float*)d_in[13];

  char* ws = (char*)d_ws;
  // [0..2M): W2 hi/lo splits (dead after proj GEMM) -> reused as Oh fp32 (exactly 2MB)
  unsigned short* W2q_hi = (unsigned short*)(ws + 0);
  unsigned short* W2q_lo = (unsigned short*)(ws + 524288);
  unsigned short* W2k_hi = (unsigned short*)(ws + 1048576);
  unsigned short* W2k_lo = (unsigned short*)(ws + 1572864);
  float* Oh = (float*)(ws + 0);
  unsigned short* Wvh = (unsigned short*)(ws + 2097152);
  unsigned short* Wvl = (unsigned short*)(ws + 2621440);
  unsigned short* Woh = (unsigned short*)(ws + 3145728);
  unsigned short* Wol = (unsigned short*)(ws + 3670016);
  float* b2q  = (float*)(ws + 4194304);
  float* b2k  = (float*)(ws + 4196352);
  float* av2g = (float*)(ws + 4198400);
  float* qpT  = (float*)(ws + 4198656);
  float* kp   = (float*)(ws + 6295808);
  float* Vw   = (float*)(ws + 8392960);   // end 10490112 (~R3-proven envelope)

  SplitArgs sa;
  sa.src[0] = Wv_; sa.hi[0] = Wvh; sa.lo[0] = Wvl;
  sa.src[1] = Wo_; sa.hi[1] = Woh; sa.lo[1] = Wol;
  split2<<<dim3(256, 2, 1), 256, 0, stream>>>(sa);

  prep_all<<<dim3(1025, 2, 1), 256, 0, stream>>>(Wq_, Aq_, Wk_, Ak_, bq_, bk_, av_,
                                                 W2q_hi, W2q_lo, W2k_hi, W2k_lo,
                                                 b2q, b2k, av2g);

  GemmArgs ga;
  ga.g[0] = { q_in, W2q_hi, W2q_lo, b2q, qpT, 1 };
  ga.g[1] = { k_in, W2k_hi, W2k_lo, b2k, kp,  0 };
  ga.g[2] = { v_in, Wvh,    Wvl,    bv_, Vw,  0 };
  gemm_nk<<<dim3(16, 8, 3), 256, 0, stream>>>(ga);

  attn_kernel<<<dim3(32, 16, 1), 512, 0, stream>>>(qpT, kp, Vw, av2g, Oh);

  GemmArgs go;
  go.g[0] = { Oh, Woh, Wol, bo_, (float*)d_out, 0 };
  go.g[1] = go.g[0];
  go.g[2] = go.g[0];
  gemm_nk<<<dim3(16, 8, 1), 256, 0, stream>>>(go);
}

// Round 8
// 227.756 us; speedup vs baseline: 1.1475x; 1.0018x over previous
//
#include <hip/hip_runtime.h>

#define LOG2E 1.4426950408889634f

typedef __bf16 bf16x8 __attribute__((ext_vector_type(8)));
typedef float f32x4 __attribute__((ext_vector_type(4)));

__device__ __forceinline__ unsigned short bfb(__bf16 b){
  union { __bf16 b; unsigned short u; } z; z.b = b; return z.u;
}
__device__ __forceinline__ void split8(const float* __restrict__ p, bf16x8& hi, bf16x8& lo){
  #pragma unroll
  for (int j = 0; j < 8; j++){
    float f = p[j];
    __bf16 h = (__bf16)f;
    hi[j] = h;
    lo[j] = (__bf16)(f - (float)h);
  }
}

// ---------------- split2: fp32 -> bf16 hi/lo for Wv, Wo (262144 elements each) ----------
struct SplitArgs { const float* src[2]; unsigned short* hi[2]; unsigned short* lo[2]; };
__global__ __launch_bounds__(256) void split2(SplitArgs sa){
  const float* src = sa.src[blockIdx.y];
  unsigned short* hi = sa.hi[blockIdx.y];
  unsigned short* lo = sa.lo[blockIdx.y];
  int base = (blockIdx.x * 256 + threadIdx.x) * 4;
  float4 v = *(const float4*)(src + base);
  ushort4 h, l;
  float f; __bf16 hb;
  f = v.x; hb = (__bf16)f; h.x = bfb(hb); l.x = bfb((__bf16)(f - (float)hb));
  f = v.y; hb = (__bf16)f; h.y = bfb(hb); l.y = bfb((__bf16)(f - (float)hb));
  f = v.z; hb = (__bf16)f; h.z = bfb(hb); l.z = bfb((__bf16)(f - (float)hb));
  f = v.w; hb = (__bf16)f; h.w = bfb(hb); l.w = bfb((__bf16)(f - (float)hb));
  *(ushort4*)(hi + base) = h;
  *(ushort4*)(lo + base) = l;
}

// ---------------- prep: W2 fold+split + folded biases + av2 ----------------
__global__ __launch_bounds__(256) void prep_all(
    const float* __restrict__ Wq, const float* __restrict__ Aq,
    const float* __restrict__ Wk, const float* __restrict__ Ak,
    const float* __restrict__ bq, const float* __restrict__ bk,
    const float* __restrict__ av,
    unsigned short* __restrict__ W2q_hi, unsigned short* __restrict__ W2q_lo,
    unsigned short* __restrict__ W2k_hi, unsigned short* __restrict__ W2k_lo,
    float* __restrict__ b2q, float* __restrict__ b2k, float* __restrict__ av2g){
  if (blockIdx.x == 1024){
    if (blockIdx.y == 0){
      #pragma unroll
      for (int rep = 0; rep < 2; rep++){
        int n = rep * 256 + threadIdx.x;
        int h = n >> 6, e = n & 63;
        float aq = 0.f, ak = 0.f;
        for (int c = 0; c < 64; c++){
          aq += Aq[e*64 + c] * bq[h*64 + c];
          ak += Ak[e*64 + c] * bk[h*64 + c];
        }
        b2q[n] = aq * (2.f * LOG2E);
        b2k[n] = ak * (2.f * LOG2E);
      }
    } else {
      if (threadIdx.x < 64) av2g[threadIdx.x] = -2.f * LOG2E * av[threadIdx.x];
    }
    return;
  }
  const float* W  = blockIdx.y ? Wk : Wq;
  const float* Am = blockIdx.y ? Ak : Aq;
  unsigned short* WH = blockIdx.y ? W2k_hi : W2q_hi;
  unsigned short* WL = blockIdx.y ? W2k_lo : W2q_lo;
  int idx = blockIdx.x * 256 + threadIdx.x;
  int n = idx >> 9, k = idx & 511;
  int h = n >> 6, e = n & 63;
  float acc = 0.f;
  #pragma unroll 8
  for (int c = 0; c < 64; c++)
    acc += Am[e*64 + c] * W[(h*64 + c)*512 + k];
  float v = acc * (2.f * LOG2E);
  __bf16 hb = (__bf16)v;
  WH[n*512 + k] = bfb(hb);
  WL[n*512 + k] = bfb((__bf16)(v - (float)hb));
}

// ---------------- MFMA GEMM: C[1024][512] = A(fp32) * B^T(pre-split hi/lo) + bias ----------
struct GemmBatch {
  const float* Af;
  const unsigned short *Bh, *Bl;
  const float* bias;
  float* Cf;
  int transposed;                  // 1: qpT layout ((b*8+h)*64+dk)*512 + i
};
struct GemmArgs { GemmBatch g[3]; };

__global__ __launch_bounds__(256) void gemm_nk(GemmArgs ga){
  GemmBatch gb = ga.g[blockIdx.z];
  const int lane = threadIdx.x & 63;
  const int w    = threadIdx.x >> 6;
  const int l15  = lane & 15, quad = lane >> 4;
  const int m  = blockIdx.x * 64 + w * 16 + l15;
  const int nb = blockIdx.y * 64 + l15;
  const float* Arow = gb.Af + (size_t)m * 512;
  f32x4 ac0 = {0.f,0.f,0.f,0.f}, ac1 = ac0, ac2 = ac0, ac3 = ac0;

  #pragma unroll 2
  for (int ks = 0; ks < 16; ks++){
    int ko = ks * 32 + quad * 8;
    bf16x8 ah, al;
    split8(Arow + ko, ah, al);
    #pragma unroll
    for (int t = 0; t < 4; t++){
      bf16x8 bh = *(const bf16x8*)(gb.Bh + (size_t)(nb + t*16) * 512 + ko);
      bf16x8 bl = *(const bf16x8*)(gb.Bl + (size_t)(nb + t*16) * 512 + ko);
      f32x4& ac = (t==0)?ac0:(t==1)?ac1:(t==2)?ac2:ac3;
      ac = __builtin_amdgcn_mfma_f32_16x16x32_bf16(ah, bh, ac, 0, 0, 0);
      ac = __builtin_amdgcn_mfma_f32_16x16x32_bf16(al, bh, ac, 0, 0, 0);
      ac = __builtin_amdgcn_mfma_f32_16x16x32_bf16(ah, bl, ac, 0, 0, 0);
    }
  }

  const int mrow = blockIdx.x * 64 + w * 16 + quad * 4;
  #pragma unroll
  for (int t = 0; t < 4; t++){
    f32x4 v = (t==0)?ac0:(t==1)?ac1:(t==2)?ac2:ac3;
    int n = blockIdx.y * 64 + t * 16 + l15;
    float bs = gb.bias[n];
    #pragma unroll
    for (int r = 0; r < 4; r++){
      float val = v[r] + bs;
      int m2 = mrow + r;
      if (gb.transposed){
        gb.Cf[(size_t)(((m2 >> 9) * 8 + (n >> 6)) * 64 + (n & 63)) * 512 + (m2 & 511)] = val;
      } else {
        gb.Cf[(size_t)m2 * 512 + n] = val;
      }
    }
  }
}

// ---------------- fused additive-attention core (MFMA PV, pipelined 2-barrier chunks) ----
// grid (32,16): x = 16-row query block, y = bh. 512 thr = 8 waves.
// bufA = K chunk, bufB = V chunk (both transposed [d][j], stride 130).
// X phase: score from A + stage V->B.  Y phase: PV MFMA from B + stage K_{c+1}->A.
__global__ __launch_bounds__(512, 4) void attn_kernel(
    const float* __restrict__ qpT, const float* __restrict__ kp,
    const float* __restrict__ Vv, const float* __restrict__ av2g,
    float* __restrict__ Oh){
  __shared__ float bufA[64 * 130];
  __shared__ float bufB[64 * 130];
  __shared__ unsigned short pcb[2 * 16 * 136];
  __shared__ float dn[16];
  float* cmb = bufA;

  const int tid = threadIdx.x, lane = tid & 63, w = tid >> 6;
  const int l15 = lane & 15, quad = lane >> 4;
  const int bh = blockIdx.y;
  const int i0 = blockIdx.x * 16;
  const size_t kbase = (size_t)(bh >> 3) * 512 * 512 + (size_t)(bh & 7) * 64;
  const int r0 = __builtin_amdgcn_readfirstlane(2 * w);
  const size_t qbase = (size_t)bh * 64 * 512 + i0 + r0;
  const int ntile = w & 3, khalf = w >> 2;

  float den0 = 0.f, den1 = 0.f;
  f32x4 Cacc = {0.f, 0.f, 0.f, 0.f};

  { // init: stage K_0 -> bufA
    #pragma unroll
    for (int m = 0; m < 8; m++){
      int i = w + 8 * m;
      float a = kp[kbase + (size_t)(2*i    ) * 512 + lane];
      float b = kp[kbase + (size_t)(2*i + 1) * 512 + lane];
      *(float2*)&bufA[lane * 130 + 2*i] = make_float2(a, b);
    }
  }
  __syncthreads();

  for (int c = 0; c < 4; c++){
    // ---- X phase: V_c global->regs, score from bufA, V regs->bufB, publish P ----
    float va[8], vb[8];
    #pragma unroll
    for (int m = 0; m < 8; m++){
      int i = w + 8 * m;
      va[m] = Vv[kbase + (size_t)(c*128 + 2*i    ) * 512 + lane];
      vb[m] = Vv[kbase + (size_t)(c*128 + 2*i + 1) * 512 + lane];
    }
    float s00 = 0.f, s01 = 0.f, s10 = 0.f, s11 = 0.f;
    #pragma unroll 4
    for (int d = 0; d < 64; d++){
      float2 qv = *(const float2*)(qpT + qbase + (size_t)d * 512);  // wave-uniform
      float a2 = av2g[d];                                           // wave-uniform
      float2 kk = *(const float2*)&bufA[d * 130 + 2 * lane];
      s00 += a2 * __builtin_amdgcn_rcpf(1.f + __builtin_amdgcn_exp2f(qv.x + kk.x));
      s01 += a2 * __builtin_amdgcn_rcpf(1.f + __builtin_amdgcn_exp2f(qv.x + kk.y));
      s10 += a2 * __builtin_amdgcn_rcpf(1.f + __builtin_amdgcn_exp2f(qv.y + kk.x));
      s11 += a2 * __builtin_amdgcn_rcpf(1.f + __builtin_amdgcn_exp2f(qv.y + kk.y));
    }
    float e00 = __builtin_amdgcn_exp2f(s00);
    float e01 = __builtin_amdgcn_exp2f(s01);
    float e10 = __builtin_amdgcn_exp2f(s10);
    float e11 = __builtin_amdgcn_exp2f(s11);
    den0 += e00 + e01; den1 += e10 + e11;
    {
      __bf16 h00 = (__bf16)e00, h01 = (__bf16)e01, h10 = (__bf16)e10, h11 = (__bf16)e11;
      ushort2 hi0 = { bfb(h00), bfb(h01) };
      ushort2 hi1 = { bfb(h10), bfb(h11) };
      ushort2 lo0 = { bfb((__bf16)(e00 - (float)h00)), bfb((__bf16)(e01 - (float)h01)) };
      ushort2 lo1 = { bfb((__bf16)(e10 - (float)h10)), bfb((__bf16)(e11 - (float)h11)) };
      *(ushort2*)&pcb[(0*16 + r0    ) * 136 + 2*lane] = hi0;
      *(ushort2*)&pcb[(0*16 + r0 + 1) * 136 + 2*lane] = hi1;
      *(ushort2*)&pcb[(1*16 + r0    ) * 136 + 2*lane] = lo0;
      *(ushort2*)&pcb[(1*16 + r0 + 1) * 136 + 2*lane] = lo1;
    }
    #pragma unroll
    for (int m = 0; m < 8; m++){
      int i = w + 8 * m;
      *(float2*)&bufB[lane * 130 + 2*i] = make_float2(va[m], vb[m]);
    }
    __syncthreads();

    // ---- Y phase: K_{c+1} global->regs, PV MFMA from bufB/pcb, K regs->bufA ----
    float ka[8], kb[8];
    if (c < 3){
      #pragma unroll
      for (int m = 0; m < 8; m++){
        int i = w + 8 * m;
        ka[m] = kp[kbase + (size_t)((c+1)*128 + 2*i    ) * 512 + lane];
        kb[m] = kp[kbase + (size_t)((c+1)*128 + 2*i + 1) * 512 + lane];
      }
    }
    #pragma unroll
    for (int kk2 = 0; kk2 < 2; kk2++){
      int k0 = (khalf * 2 + kk2) * 32 + quad * 8;
      bf16x8 ph = *(const bf16x8*)&pcb[(0*16 + l15) * 136 + k0];
      bf16x8 pl = *(const bf16x8*)&pcb[(1*16 + l15) * 136 + k0];
      const float* vp = &bufB[(ntile*16 + l15) * 130 + k0];
      bf16x8 vh, vl;
      #pragma unroll
      for (int j = 0; j < 8; j++){
        float f = vp[j];
        __bf16 h = (__bf16)f;
        vh[j] = h; vl[j] = (__bf16)(f - (float)h);
      }
      Cacc = __builtin_amdgcn_mfma_f32_16x16x32_bf16(ph, vh, Cacc, 0, 0, 0);
      Cacc = __builtin_amdgcn_mfma_f32_16x16x32_bf16(pl, vh, Cacc, 0, 0, 0);
      Cacc = __builtin_amdgcn_mfma_f32_16x16x32_bf16(ph, vl, Cacc, 0, 0, 0);
    }
    if (c < 3){
      #pragma unroll
      for (int m = 0; m < 8; m++){
        int i = w + 8 * m;
        *(float2*)&bufA[lane * 130 + 2*i] = make_float2(ka[m], kb[m]);
      }
    }
    __syncthreads();
  }

  // den reduction: wave w owns rows 2w, 2w+1
  #pragma unroll
  for (int off = 1; off < 64; off <<= 1){
    den0 += __shfl_xor(den0, off, 64);
    den1 += __shfl_xor(den1, off, 64);
  }
  if (lane == 0){ dn[r0] = den0; dn[r0 + 1] = den1; }
  __syncthreads();
  if (w >= 4){
    #pragma unroll
    for (int r = 0; r < 4; r++) cmb[(w - 4) * 256 + lane * 4 + r] = Cacc[r];
  }
  __syncthreads();
  if (w < 4){
    #pragma unroll
    for (int r = 0; r < 4; r++){
      float cv = Cacc[r] + cmb[w * 256 + lane * 4 + r];
      int row = quad * 4 + r;
      int d = ntile * 16 + l15;                   // ntile == w here
      Oh[kbase + (size_t)(i0 + row) * 512 + d] = cv / dn[row];
    }
  }
}

// ---------------- launch ----------------
extern "C" void kernel_launch(void* const* d_in, const int* in_sizes, int n_in,
                              void* d_out, int out_size, void* d_ws, size_t ws_size,
                              hipStream_t stream){
  const float* q_in = (const float*)d_in[0];
  const float* k_in = (const float*)d_in[1];
  const float* v_in = (const float*)d_in[2];
  const float* Wq_  = (const float*)d_in[3];
  const float* bq_  = (const float*)d_in[4];
  const float* Wk_  = (const float*)d_in[5];
  const float* bk_  = (const float*)d_in[6];
  const float* Wv_  = (const float*)d_in[7];
  const float* bv_  = (const float*)d_in[8];
  const float* Wo_  = (const float*)d_in[9];
  const float* bo_  = (const float*)d_in[10];
  const float* Aq_  = (const float*)d_in[11];
  const float* Ak_  = (const float*)d_in[12];
  const float* av_  = (const float*)d_in[13];

  char* ws = (char*)d_ws;
  unsigned short* W2q_hi = (unsigned short*)(ws + 0);
  unsigned short* W2q_lo = (unsigned short*)(ws + 524288);
  unsigned short* W2k_hi = (unsigned short*)(ws + 1048576);
  unsigned short* W2k_lo = (unsigned short*)(ws + 1572864);
  float* Oh = (float*)(ws + 0);
  unsigned short* Wvh = (unsigned short*)(ws + 2097152);
  unsigned short* Wvl = (unsigned short*)(ws + 2621440);
  unsigned short* Woh = (unsigned short*)(ws + 3145728);
  unsigned short* Wol = (unsigned short*)(ws + 3670016);
  float* b2q  = (float*)(ws + 4194304);
  float* b2k  = (float*)(ws + 4196352);
  float* av2g = (float*)(ws + 4198400);
  float* qpT  = (float*)(ws + 4198656);
  float* kp   = (float*)(ws + 6295808);
  float* Vw   = (float*)(ws + 8392960);

  SplitArgs sa;
  sa.src[0] = Wv_; sa.hi[0] = Wvh; sa.lo[0] = Wvl;
  sa.src[1] = Wo_; sa.hi[1] = Woh; sa.lo[1] = Wol;
  split2<<<dim3(256, 2, 1), 256, 0, stream>>>(sa);

  prep_all<<<dim3(1025, 2, 1), 256, 0, stream>>>(Wq_, Aq_, Wk_, Ak_, bq_, bk_, av_,
                                                 W2q_hi, W2q_lo, W2k_hi, W2k_lo,
                                                 b2q, b2k, av2g);

  GemmArgs ga;
  ga.g[0] = { q_in, W2q_hi, W2q_lo, b2q, qpT, 1 };
  ga.g[1] = { k_in, W2k_hi, W2k_lo, b2k, kp,  0 };
  ga.g[2] = { v_in, Wvh,    Wvl,    bv_, Vw,  0 };
  gemm_nk<<<dim3(16, 8, 3), 256, 0, stream>>>(ga);

  attn_kernel<<<dim3(32, 16, 1), 512, 0, stream>>>(qpT, kp, Vw, av2g, Oh);

  GemmArgs go;
  go.g[0] = { Oh, Woh, Wol, bo_, (float*)d_out, 0 };
  go.g[1] = go.g[0];
  go.g[2] = go.g[0];
  gemm_nk<<<dim3(16, 8, 1), 256, 0, stream>>>(go);
}